// Round 1
// baseline (258.662 us; speedup 1.0000x reference)
//
#include <hip/hip_runtime.h>

// LJ 12-6 over a neighbor list.
// Inputs (setup_inputs order):
//   d_in[0] R       float32 [N,3]        (in_sizes[0] = 3N)
//   d_in[1] epsilon float32 [1]
//   d_in[2] sigma   float32 [1]
//   d_in[3] cutoff  float32 [1]
//   d_in[4] idx_i   int32   [P]
//   d_in[5] idx_j   int32   [P]
// Output d_out: energy [N] floats, then forces [N,3] floats (flat concat).

__global__ void __launch_bounds__(256) pad_R_kernel(
    const float* __restrict__ R, float4* __restrict__ Rp, int n_atoms)
{
    int a = blockIdx.x * blockDim.x + threadIdx.x;
    if (a < n_atoms) {
        // 12B read -> 16B aligned write; guarantees single-transaction gathers later
        Rp[a] = make_float4(R[3 * a + 0], R[3 * a + 1], R[3 * a + 2], 0.0f);
    }
}

// PADDED=true : gather from float4 Rp in ws (aligned, 1 txn)
// PADDED=false: gather 3 floats straight from R (fallback if ws too small)
template <bool PADDED>
__global__ void __launch_bounds__(256) lj_pairs_kernel(
    const float* __restrict__ R,
    const float4* __restrict__ Rp,
    const int4* __restrict__ idx_i4,
    const int4* __restrict__ idx_j4,
    const float* __restrict__ eps_p,
    const float* __restrict__ sig_p,
    const float* __restrict__ cut_p,
    float* __restrict__ energy,   // [N]
    float* __restrict__ forces,   // [N,3]
    int n_quads)
{
    int t = blockIdx.x * blockDim.x + threadIdx.x;
    if (t >= n_quads) return;

    const float eps  = eps_p[0];
    const float sig  = sig_p[0];
    const float cut  = cut_p[0];
    const float s2   = sig * sig;
    const float cut2 = cut * cut;

    int4 ii = idx_i4[t];
    int4 jj = idx_j4[t];

    const int is[4] = { ii.x, ii.y, ii.z, ii.w };
    const int js[4] = { jj.x, jj.y, jj.z, jj.w };

#pragma unroll
    for (int k = 0; k < 4; ++k) {
        const int i = is[k];
        const int j = js[k];
        float dx, dy, dz;
        if (PADDED) {
            float4 Ri = Rp[i];
            float4 Rj = Rp[j];
            dx = Ri.x - Rj.x; dy = Ri.y - Rj.y; dz = Ri.z - Rj.z;
        } else {
            dx = R[3 * i + 0] - R[3 * j + 0];
            dy = R[3 * i + 1] - R[3 * j + 1];
            dz = R[3 * i + 2] - R[3 * j + 2];
        }
        const float r2 = dx * dx + dy * dy + dz * dz;
        // ~1.9% of pairs pass -> skip atomics for the rest
        if (r2 < cut2 && r2 > 1e-10f) {
            const float inv  = 1.0f / r2;
            const float sr2  = s2 * inv;
            const float sr6  = sr2 * sr2 * sr2;
            const float sr12 = sr6 * sr6;
            const float e    = 2.0f * eps * (sr12 - sr6);              // 0.5 * 4eps
            const float f    = 24.0f * eps * (2.0f * sr12 - sr6) * inv;
            atomicAdd(&energy[i], e);
            atomicAdd(&forces[3 * i + 0], f * dx);
            atomicAdd(&forces[3 * i + 1], f * dy);
            atomicAdd(&forces[3 * i + 2], f * dz);
        }
    }
}

// Scalar tail (n_pairs % 4 != 0) — not hit for P=12.8M but kept for safety.
template <bool PADDED>
__global__ void lj_pairs_tail_kernel(
    const float* __restrict__ R,
    const float4* __restrict__ Rp,
    const int* __restrict__ idx_i,
    const int* __restrict__ idx_j,
    const float* __restrict__ eps_p,
    const float* __restrict__ sig_p,
    const float* __restrict__ cut_p,
    float* __restrict__ energy,
    float* __restrict__ forces,
    int start, int n_pairs)
{
    int p = start + blockIdx.x * blockDim.x + threadIdx.x;
    if (p >= n_pairs) return;
    const float eps  = eps_p[0];
    const float sig  = sig_p[0];
    const float cut  = cut_p[0];
    const float s2   = sig * sig;
    const float cut2 = cut * cut;
    const int i = idx_i[p];
    const int j = idx_j[p];
    float dx, dy, dz;
    if (PADDED) {
        float4 Ri = Rp[i];
        float4 Rj = Rp[j];
        dx = Ri.x - Rj.x; dy = Ri.y - Rj.y; dz = Ri.z - Rj.z;
    } else {
        dx = R[3 * i + 0] - R[3 * j + 0];
        dy = R[3 * i + 1] - R[3 * j + 1];
        dz = R[3 * i + 2] - R[3 * j + 2];
    }
    const float r2 = dx * dx + dy * dy + dz * dz;
    if (r2 < cut2 && r2 > 1e-10f) {
        const float inv  = 1.0f / r2;
        const float sr2  = s2 * inv;
        const float sr6  = sr2 * sr2 * sr2;
        const float sr12 = sr6 * sr6;
        const float e    = 2.0f * eps * (sr12 - sr6);
        const float f    = 24.0f * eps * (2.0f * sr12 - sr6) * inv;
        atomicAdd(&energy[i], e);
        atomicAdd(&forces[3 * i + 0], f * dx);
        atomicAdd(&forces[3 * i + 1], f * dy);
        atomicAdd(&forces[3 * i + 2], f * dz);
    }
}

extern "C" void kernel_launch(void* const* d_in, const int* in_sizes, int n_in,
                              void* d_out, int out_size, void* d_ws, size_t ws_size,
                              hipStream_t stream) {
    const float* R     = (const float*)d_in[0];
    const float* eps_p = (const float*)d_in[1];
    const float* sig_p = (const float*)d_in[2];
    const float* cut_p = (const float*)d_in[3];
    const int*   idx_i = (const int*)d_in[4];
    const int*   idx_j = (const int*)d_in[5];

    const int n_atoms = in_sizes[0] / 3;
    const int n_pairs = in_sizes[4];

    float* energy = (float*)d_out;                 // [N]
    float* forces = (float*)d_out + n_atoms;       // [N,3]

    // d_out is re-poisoned 0xAA before every timed call — zero it.
    hipMemsetAsync(d_out, 0, (size_t)out_size * sizeof(float), stream);

    const bool padded = ws_size >= (size_t)n_atoms * sizeof(float4);
    float4* Rp = (float4*)d_ws;

    if (padded) {
        int blocks = (n_atoms + 255) / 256;
        pad_R_kernel<<<blocks, 256, 0, stream>>>(R, Rp, n_atoms);
    }

    const int n_quads = n_pairs >> 2;
    const int tail    = n_pairs & 3;
    if (n_quads > 0) {
        int blocks = (n_quads + 255) / 256;
        if (padded) {
            lj_pairs_kernel<true><<<blocks, 256, 0, stream>>>(
                R, Rp, (const int4*)idx_i, (const int4*)idx_j,
                eps_p, sig_p, cut_p, energy, forces, n_quads);
        } else {
            lj_pairs_kernel<false><<<blocks, 256, 0, stream>>>(
                R, Rp, (const int4*)idx_i, (const int4*)idx_j,
                eps_p, sig_p, cut_p, energy, forces, n_quads);
        }
    }
    if (tail > 0) {
        const int start = n_quads << 2;
        if (padded) {
            lj_pairs_tail_kernel<true><<<1, 64, 0, stream>>>(
                R, Rp, idx_i, idx_j, eps_p, sig_p, cut_p, energy, forces, start, n_pairs);
        } else {
            lj_pairs_tail_kernel<false><<<1, 64, 0, stream>>>(
                R, Rp, idx_i, idx_j, eps_p, sig_p, cut_p, energy, forces, start, n_pairs);
        }
    }
}

// Round 2
// 241.618 us; speedup vs baseline: 1.0705x; 1.0705x over previous
//
#include <hip/hip_runtime.h>

// LJ 12-6 over a neighbor list — round 2: MLP-batched gathers.
// Inputs (setup_inputs order):
//   d_in[0] R       float32 [N,3]
//   d_in[1] epsilon float32 [1]
//   d_in[2] sigma   float32 [1]
//   d_in[3] cutoff  float32 [1]
//   d_in[4] idx_i   int32   [P]
//   d_in[5] idx_j   int32   [P]
// Output d_out: energy [N], then forces [N,3] (flat concat).

typedef int   v4i __attribute__((ext_vector_type(4)));
typedef float v4f __attribute__((ext_vector_type(4)));

__global__ void __launch_bounds__(256) pad_R_kernel(
    const float* __restrict__ R, v4f* __restrict__ Rp, int n_atoms)
{
    int a = blockIdx.x * blockDim.x + threadIdx.x;
    if (a < n_atoms) {
        v4f v;
        v.x = R[3 * a + 0];
        v.y = R[3 * a + 1];
        v.z = R[3 * a + 2];
        v.w = 0.0f;
        Rp[a] = v;  // 16B aligned: gathers later are single-transaction
    }
}

#define PAIRS_PER_THREAD 8

__global__ void __launch_bounds__(256) lj_pairs_kernel(
    const v4f* __restrict__ Rp,
    const v4i* __restrict__ idx_i4,
    const v4i* __restrict__ idx_j4,
    const float* __restrict__ eps_p,
    const float* __restrict__ sig_p,
    const float* __restrict__ cut_p,
    float* __restrict__ energy,   // [N]
    float* __restrict__ forces,   // [N,3]
    int n_oct)                    // n_pairs / 8
{
    int t = blockIdx.x * blockDim.x + threadIdx.x;
    if (t >= n_oct) return;

    const float eps  = eps_p[0];
    const float sig  = sig_p[0];
    const float cut  = cut_p[0];
    const float s2   = sig * sig;
    const float cut2 = cut * cut;

    // idx streamed once (102 MB): nontemporal so it doesn't evict Rp from L2.
    v4i ii0 = __builtin_nontemporal_load(idx_i4 + 2 * t);
    v4i ii1 = __builtin_nontemporal_load(idx_i4 + 2 * t + 1);
    v4i jj0 = __builtin_nontemporal_load(idx_j4 + 2 * t);
    v4i jj1 = __builtin_nontemporal_load(idx_j4 + 2 * t + 1);

    int is[PAIRS_PER_THREAD] = { ii0.x, ii0.y, ii0.z, ii0.w, ii1.x, ii1.y, ii1.z, ii1.w };
    int js[PAIRS_PER_THREAD] = { jj0.x, jj0.y, jj0.z, jj0.w, jj1.x, jj1.y, jj1.z, jj1.w };

    // Phase 1: issue ALL 16 gathers before any use -> 16 outstanding vmem/wave.
    v4f Ri[PAIRS_PER_THREAD];
    v4f Rj[PAIRS_PER_THREAD];
#pragma unroll
    for (int k = 0; k < PAIRS_PER_THREAD; ++k) Ri[k] = Rp[is[k]];
#pragma unroll
    for (int k = 0; k < PAIRS_PER_THREAD; ++k) Rj[k] = Rp[js[k]];

    // Phase 2: compute + sparse atomics (~1.9% of pairs pass the cutoff).
#pragma unroll
    for (int k = 0; k < PAIRS_PER_THREAD; ++k) {
        const float dx = Ri[k].x - Rj[k].x;
        const float dy = Ri[k].y - Rj[k].y;
        const float dz = Ri[k].z - Rj[k].z;
        const float r2 = dx * dx + dy * dy + dz * dz;
        if (r2 < cut2 && r2 > 1e-10f) {
            const float inv  = 1.0f / r2;
            const float sr2  = s2 * inv;
            const float sr6  = sr2 * sr2 * sr2;
            const float sr12 = sr6 * sr6;
            const float e    = 2.0f * eps * (sr12 - sr6);              // 0.5 * 4eps
            const float f    = 24.0f * eps * (2.0f * sr12 - sr6) * inv;
            const int i = is[k];
            atomicAdd(&energy[i], e);
            atomicAdd(&forces[3 * i + 0], f * dx);
            atomicAdd(&forces[3 * i + 1], f * dy);
            atomicAdd(&forces[3 * i + 2], f * dz);
        }
    }
}

// Scalar tail for n_pairs % 8 != 0 (not hit at P = 12.8M, kept for safety).
__global__ void lj_pairs_tail_kernel(
    const v4f* __restrict__ Rp,
    const int* __restrict__ idx_i,
    const int* __restrict__ idx_j,
    const float* __restrict__ eps_p,
    const float* __restrict__ sig_p,
    const float* __restrict__ cut_p,
    float* __restrict__ energy,
    float* __restrict__ forces,
    int start, int n_pairs)
{
    int p = start + blockIdx.x * blockDim.x + threadIdx.x;
    if (p >= n_pairs) return;
    const float eps  = eps_p[0];
    const float sig  = sig_p[0];
    const float cut  = cut_p[0];
    const float s2   = sig * sig;
    const float cut2 = cut * cut;
    const int i = idx_i[p];
    const int j = idx_j[p];
    v4f Ri = Rp[i];
    v4f Rj = Rp[j];
    const float dx = Ri.x - Rj.x;
    const float dy = Ri.y - Rj.y;
    const float dz = Ri.z - Rj.z;
    const float r2 = dx * dx + dy * dy + dz * dz;
    if (r2 < cut2 && r2 > 1e-10f) {
        const float inv  = 1.0f / r2;
        const float sr2  = s2 * inv;
        const float sr6  = sr2 * sr2 * sr2;
        const float sr12 = sr6 * sr6;
        const float e    = 2.0f * eps * (sr12 - sr6);
        const float f    = 24.0f * eps * (2.0f * sr12 - sr6) * inv;
        atomicAdd(&energy[i], e);
        atomicAdd(&forces[3 * i + 0], f * dx);
        atomicAdd(&forces[3 * i + 1], f * dy);
        atomicAdd(&forces[3 * i + 2], f * dz);
    }
}

extern "C" void kernel_launch(void* const* d_in, const int* in_sizes, int n_in,
                              void* d_out, int out_size, void* d_ws, size_t ws_size,
                              hipStream_t stream) {
    const float* R     = (const float*)d_in[0];
    const float* eps_p = (const float*)d_in[1];
    const float* sig_p = (const float*)d_in[2];
    const float* cut_p = (const float*)d_in[3];
    const int*   idx_i = (const int*)d_in[4];
    const int*   idx_j = (const int*)d_in[5];

    const int n_atoms = in_sizes[0] / 3;
    const int n_pairs = in_sizes[4];

    float* energy = (float*)d_out;
    float* forces = (float*)d_out + n_atoms;

    // d_out re-poisoned 0xAA before every timed call — zero it.
    hipMemsetAsync(d_out, 0, (size_t)out_size * sizeof(float), stream);

    v4f* Rp = (v4f*)d_ws;  // ws_size (checked in round 1) >= n_atoms*16B
    {
        int blocks = (n_atoms + 255) / 256;
        pad_R_kernel<<<blocks, 256, 0, stream>>>(R, Rp, n_atoms);
    }

    const int n_oct = n_pairs / PAIRS_PER_THREAD;
    const int start = n_oct * PAIRS_PER_THREAD;
    if (n_oct > 0) {
        int blocks = (n_oct + 255) / 256;
        lj_pairs_kernel<<<blocks, 256, 0, stream>>>(
            Rp, (const v4i*)idx_i, (const v4i*)idx_j,
            eps_p, sig_p, cut_p, energy, forces, n_oct);
    }
    if (start < n_pairs) {
        lj_pairs_tail_kernel<<<1, 64, 0, stream>>>(
            Rp, idx_i, idx_j, eps_p, sig_p, cut_p, energy, forces, start, n_pairs);
    }
}